// Round 7
// baseline (10636.722 us; speedup 1.0000x reference)
//
#include <hip/hip_runtime.h>
#include <cstdint>

#define B_   8
#define S_   512
#define D_   768
#define C_   9
#define BS_  4096   // B*S

typedef unsigned long long u64;

// ---------------------------------------------------------------------------
// embedding gather: x[row][0:768] = emb[ids[row]][0:768]
// ---------------------------------------------------------------------------
__global__ __launch_bounds__(192) void k_embed(const int* __restrict__ ids,
                                               const float* __restrict__ emb,
                                               float* __restrict__ x) {
  int row = blockIdx.x;
  int id = ids[row];
  const float4* src = (const float4*)(emb + (size_t)id * D_);
  float4* dst = (float4*)(x + (size_t)row * D_);
  dst[threadIdx.x] = src[threadIdx.x];
}

// ---------------------------------------------------------------------------
// generic fp32 GEMM: C[M,N] = A[M,K] @ W[N,K]^T + bias[N]
// act: 0 none 1 relu 2 sigmoid ; mode: 0 row-major C, 1 lstm-gates layout
// gates layout (mode 1): C[((d*512+t)*768 + u)*32 + g*8 + bb]
//   where m = bb*512+t, n = d*3072 + g*768 + u
// ---------------------------------------------------------------------------
#define GIDX(k, m) ((k)*144 + (m) + (((m) >> 5) << 2))

__global__ __launch_bounds__(256) void k_gemm(const float* __restrict__ A,
                                              const float* __restrict__ W,
                                              const float* __restrict__ bias,
                                              float* __restrict__ C,
                                              int M, int N, int K, int act, int mode) {
  __shared__ float As[2304];
  __shared__ float Bs[2304];
  int bm0 = blockIdx.y * 128, bn0 = blockIdx.x * 128;
  int tid = threadIdx.x;
  int tm = tid >> 4, tn = tid & 15;
  float acc[8][8];
#pragma unroll
  for (int i = 0; i < 8; ++i)
#pragma unroll
    for (int j = 0; j < 8; ++j) acc[i][j] = 0.f;

  for (int k0 = 0; k0 < K; k0 += 16) {
    __syncthreads();
#pragma unroll
    for (int j = 0; j < 2; ++j) {
      int f4 = tid + j * 256;          // 0..511
      int r = f4 >> 2;
      int kq = (f4 & 3) * 4;
      float4 va = *(const float4*)(A + (size_t)(bm0 + r) * K + k0 + kq);
      As[GIDX(kq + 0, r)] = va.x; As[GIDX(kq + 1, r)] = va.y;
      As[GIDX(kq + 2, r)] = va.z; As[GIDX(kq + 3, r)] = va.w;
      float4 vb = *(const float4*)(W + (size_t)(bn0 + r) * K + k0 + kq);
      Bs[GIDX(kq + 0, r)] = vb.x; Bs[GIDX(kq + 1, r)] = vb.y;
      Bs[GIDX(kq + 2, r)] = vb.z; Bs[GIDX(kq + 3, r)] = vb.w;
    }
    __syncthreads();
#pragma unroll
    for (int kk = 0; kk < 16; ++kk) {
      float a[8], b[8];
      *(float4*)&a[0] = *(const float4*)&As[GIDX(kk, tm * 8)];
      *(float4*)&a[4] = *(const float4*)&As[GIDX(kk, tm * 8 + 4)];
      *(float4*)&b[0] = *(const float4*)&Bs[GIDX(kk, tn * 8)];
      *(float4*)&b[4] = *(const float4*)&Bs[GIDX(kk, tn * 8 + 4)];
#pragma unroll
      for (int i = 0; i < 8; ++i)
#pragma unroll
        for (int j = 0; j < 8; ++j) acc[i][j] += a[i] * b[j];
    }
  }

  float bv[8];
#pragma unroll
  for (int j = 0; j < 8; ++j) bv[j] = bias[bn0 + tn * 8 + j];
#pragma unroll
  for (int i = 0; i < 8; ++i) {
    int row = bm0 + tm * 8 + i;
    float o[8];
#pragma unroll
    for (int j = 0; j < 8; ++j) {
      float v = acc[i][j] + bv[j];
      if (act == 1) v = fmaxf(v, 0.f);
      else if (act == 2) v = 1.f / (1.f + expf(-v));
      o[j] = v;
    }
    if (mode == 0) {
      float* cp = C + (size_t)row * N + bn0 + tn * 8;
      *(float4*)cp = make_float4(o[0], o[1], o[2], o[3]);
      *(float4*)(cp + 4) = make_float4(o[4], o[5], o[6], o[7]);
    } else {
      int bb = row >> 9, t = row & 511;
#pragma unroll
      for (int j = 0; j < 8; ++j) {
        unsigned n = bn0 + tn * 8 + j;
        unsigned d = n / 3072u;
        unsigned n2 = n - d * 3072u;
        unsigned g = n2 / 768u;
        unsigned u = n2 - g * 768u;
        C[(((size_t)(d * 512 + t) * 768 + u) << 5) + g * 8 + bb] = o[j];
      }
    }
  }
}

// ---------------------------------------------------------------------------
// highway combine (in place): x = t*hh + (1-t)*x
// ---------------------------------------------------------------------------
__global__ __launch_bounds__(256) void k_highway(float* __restrict__ x,
                                                 const float* __restrict__ hh,
                                                 const float* __restrict__ tt) {
  const int n4 = BS_ * D_ / 4;
  for (int i = blockIdx.x * 256 + threadIdx.x; i < n4; i += gridDim.x * 256) {
    float4 xv = ((const float4*)x)[i];
    float4 hv = ((const float4*)hh)[i];
    float4 tv = ((const float4*)tt)[i];
    xv.x = tv.x * hv.x + (1.f - tv.x) * xv.x;
    xv.y = tv.y * hv.y + (1.f - tv.y) * xv.y;
    xv.z = tv.z * hv.z + (1.f - tv.z) * xv.z;
    xv.w = tv.w * hv.w + (1.f - tv.w) * xv.w;
    ((float4*)x)[i] = xv;
  }
}

// ---------------------------------------------------------------------------
// multi-head attention. qkv: [4096][2304] (q|k|v). out: [4096][768].
// ---------------------------------------------------------------------------
__global__ __launch_bounds__(256) void k_attn(const float* __restrict__ qkv,
                                              float* __restrict__ out) {
  __shared__ float Qs[16 * 100];
  __shared__ float Ks[32 * 101];
  __shared__ float Ps[16 * 513];
  int bh = blockIdx.x;          // 0..63
  int b = bh >> 3, h = bh & 7;
  int q0 = blockIdx.y * 16;
  int tid = threadIdx.x;
  const float scale = 0.10206207261596577f;  // 1/sqrt(96)

  const float* qb = qkv + (size_t)(b * 512 + q0) * 2304 + h * 96;
  for (int i = tid; i < 16 * 96; i += 256) {
    int r = i / 96, c = i - r * 96;
    Qs[r * 100 + c] = qb[(size_t)r * 2304 + c];
  }
  int qi = tid >> 4, kseg = tid & 15;

  for (int kt = 0; kt < 16; ++kt) {
    __syncthreads();
    const float* kb = qkv + (size_t)(b * 512 + kt * 32) * 2304 + 768 + h * 96;
    for (int i = tid; i < 32 * 96; i += 256) {
      int r = i / 96, c = i - r * 96;
      Ks[r * 101 + c] = kb[(size_t)r * 2304 + c];
    }
    __syncthreads();
    int kj0 = kseg * 2;
    float s0 = 0.f, s1 = 0.f;
    const float* qrow = &Qs[qi * 100];
    const float* k0p = &Ks[kj0 * 101];
    const float* k1p = &Ks[(kj0 + 1) * 101];
#pragma unroll 8
    for (int d = 0; d < 96; ++d) {
      float qv = qrow[d];
      s0 += qv * k0p[d];
      s1 += qv * k1p[d];
    }
    Ps[qi * 513 + kt * 32 + kj0] = s0 * scale;
    Ps[qi * 513 + kt * 32 + kj0 + 1] = s1 * scale;
  }
  __syncthreads();

  {
    float m = -1e30f;
    for (int j = 0; j < 32; ++j) m = fmaxf(m, Ps[qi * 513 + kseg + j * 16]);
    m = fmaxf(m, __shfl_xor(m, 1)); m = fmaxf(m, __shfl_xor(m, 2));
    m = fmaxf(m, __shfl_xor(m, 4)); m = fmaxf(m, __shfl_xor(m, 8));
    float sum = 0.f;
    for (int j = 0; j < 32; ++j) {
      int idx = qi * 513 + kseg + j * 16;
      float e = expf(Ps[idx] - m);
      Ps[idx] = e;
      sum += e;
    }
    sum += __shfl_xor(sum, 1); sum += __shfl_xor(sum, 2);
    sum += __shfl_xor(sum, 4); sum += __shfl_xor(sum, 8);
    float inv = 1.f / sum;
    for (int j = 0; j < 32; ++j) Ps[qi * 513 + kseg + j * 16] *= inv;
  }

  float acc[6] = {0.f, 0.f, 0.f, 0.f, 0.f, 0.f};
  int d0 = kseg * 6;
  for (int kt = 0; kt < 16; ++kt) {
    __syncthreads();
    const float* vb = qkv + (size_t)(b * 512 + kt * 32) * 2304 + 1536 + h * 96;
    for (int i = tid; i < 32 * 96; i += 256) {
      int r = i / 96, c = i - r * 96;
      Ks[r * 101 + c] = vb[(size_t)r * 2304 + c];
    }
    __syncthreads();
#pragma unroll 4
    for (int kj = 0; kj < 32; ++kj) {
      float p = Ps[qi * 513 + kt * 32 + kj];
      const float* vrow = &Ks[kj * 101 + d0];
#pragma unroll
      for (int u = 0; u < 6; ++u) acc[u] += p * vrow[u];
    }
  }
  float* ob = out + (size_t)(b * 512 + q0 + qi) * 768 + h * 96 + d0;
#pragma unroll
  for (int u = 0; u < 6; ++u) ob[u] = acc[u];
}

// ---------------------------------------------------------------------------
// persistent BiLSTM, one layer, BOTH directions interleaved in EVERY WG.
// 192 WGs x 256 threads; WG owns units {wg*4+rg} (rg = wave 0..3) of dir0 AND
// dir1 (weights 2 x 48 VGPR). Per step, per dir d: poll(d) -> stage(d) ->
// sync -> publish(other dir's flag; its stores just drained by this sync) ->
// dot+reduce -> owners store h(d, step+1).  The exchange latency of dir d
// propagates while the WG computes dir (1-d)  ->  poll mostly pre-satisfied.
// lane L of a wave: k-slice ksl=L (12 floats); after 5-stage reduce-scatter
// lane L holds gate-sum idx=(L>>1)&31 = g*8+bb. Owners: even L<16 (bb=L>>1).
// ---------------------------------------------------------------------------
#define NWG 192
__global__ __launch_bounds__(256, 1) void k_lstm(const float* __restrict__ gates,
                                                 const float* __restrict__ Whh,
                                                 float* __restrict__ hbuf,
                                                 float* __restrict__ hs,
                                                 int* __restrict__ flags) {
  __shared__ float hlds0[8 * 772];
  __shared__ float hlds1[8 * 772];
  int tid = threadIdx.x;
  int wg  = blockIdx.x;
  int rg  = tid >> 6;                // wave id = unit-in-WG
  int lane = tid & 63;
  int unit = wg * 4 + rg;            // 0..767
  int idx = (lane >> 1) & 31;        // g*8+bb after reduce
  bool owner = ((lane & 1) == 0) && (lane < 16);
  int bb = lane >> 1;                // valid for owners

  // weights: dir0 & dir1, 4 gates x 3 float4 (k = jj*256 + lane*4 .. +3)
  float4 w0[4][3], w1[4][3];
#pragma unroll
  for (int j = 0; j < 4; ++j) {
    const float* p0 = Whh + ((size_t)(j * 768 + unit)) * 768 + lane * 4;
    const float* p1 = Whh + ((size_t)(3072 + j * 768 + unit)) * 768 + lane * 4;
#pragma unroll
    for (int jj = 0; jj < 3; ++jj) {
      w0[j][jj] = *(const float4*)(p0 + jj * 256);
      w1[j][jj] = *(const float4*)(p1 + jj * 256);
    }
  }

  float* hb0 = hbuf;                 // [2][8][768]
  float* hb1 = hbuf + 2 * 6144;
  int* f0 = flags;                   // [NWG*8]
  int* f1 = flags + NWG * 8;
  const float* gbase = gates + (size_t)unit * 32 + idx;

  float cst0 = 0.f, cst1 = 0.f;
  float gq0 = gbase[0];                          // (d=0,t=0)
  float gq1 = gbase[(size_t)1023 * 24576];       // (d=1,t=511)

  for (int step = 0; step < 512; ++step) {
    int t = step, t1 = 511 - step;
    float gq0n = 0.f, gq1n = 0.f;
    if (step < 511) {
      gq0n = gbase[(size_t)(t + 1) * 24576];
      gq1n = gbase[(size_t)(1022 - step) * 24576];
    }

    // ---------------- dir 0 half-step ----------------
    if (tid < NWG) {                 // A0: poll dir0 producers
      const int* fp = &f0[tid * 8];
      while (__hip_atomic_load(fp, __ATOMIC_RELAXED, __HIP_MEMORY_SCOPE_AGENT) < step)
        __builtin_amdgcn_s_sleep(2);
    }
    {                                // B0: stage h0(step)
      const float* hsrc = hb0 + (step & 1) * 6144;
#pragma unroll
      for (int i = 0; i < 6; ++i) {
        int id2 = i * 256 + tid;     // 0..1535 float4-chunks
        int b2 = id2 / 192;
        int r4 = (id2 - b2 * 192) * 4;
        const u64* src = (const u64*)(hsrc + b2 * 768 + r4);
        u64 lo = __hip_atomic_load(src,     __ATOMIC_RELAXED, __HIP_MEMORY_SCOPE_AGENT);
        u64 hi = __hip_atomic_load(src + 1, __ATOMIC_RELAXED, __HIP_MEMORY_SCOPE_AGENT);
        float* dst = &hlds0[b2 * 772 + r4];
        *(u64*)dst = lo; *(u64*)(dst + 2) = hi;
      }
    }
    __syncthreads();                 // C0 (drains D1(step-1) stores of hb1(step))
    if (tid == 0)                    // P1: hb1(step) now visible
      __hip_atomic_store(&f1[wg * 8], step, __ATOMIC_RELAXED, __HIP_MEMORY_SCOPE_AGENT);

    {                                // D0: dot + reduce + owners
      const float* hp = hlds0 + lane * 4;
      float v[32];
#pragma unroll
      for (int i = 0; i < 32; ++i) v[i] = 0.f;
#pragma unroll
      for (int jj = 0; jj < 3; ++jj)
#pragma unroll
        for (int b2 = 0; b2 < 8; ++b2) {
          float4 hv = *(const float4*)(hp + b2 * 772 + jj * 256);
#pragma unroll
          for (int j = 0; j < 4; ++j) {
            float4 w = w0[j][jj];
            v[j * 8 + b2] = fmaf(w.x, hv.x, v[j * 8 + b2]);
            v[j * 8 + b2] = fmaf(w.y, hv.y, v[j * 8 + b2]);
            v[j * 8 + b2] = fmaf(w.z, hv.z, v[j * 8 + b2]);
            v[j * 8 + b2] = fmaf(w.w, hv.w, v[j * 8 + b2]);
          }
        }
      {
        bool hi = (lane & 32) != 0;
#pragma unroll
        for (int i = 0; i < 16; ++i) {
          float keep = hi ? v[i + 16] : v[i], send = hi ? v[i] : v[i + 16];
          v[i] = keep + __shfl_xor(send, 32);
        }
      }
      {
        bool hi = (lane & 16) != 0;
#pragma unroll
        for (int i = 0; i < 8; ++i) {
          float keep = hi ? v[i + 8] : v[i], send = hi ? v[i] : v[i + 8];
          v[i] = keep + __shfl_xor(send, 16);
        }
      }
      {
        bool hi = (lane & 8) != 0;
#pragma unroll
        for (int i = 0; i < 4; ++i) {
          float keep = hi ? v[i + 4] : v[i], send = hi ? v[i] : v[i + 4];
          v[i] = keep + __shfl_xor(send, 8);
        }
      }
      {
        bool hi = (lane & 4) != 0;
#pragma unroll
        for (int i = 0; i < 2; ++i) {
          float keep = hi ? v[i + 2] : v[i], send = hi ? v[i] : v[i + 2];
          v[i] = keep + __shfl_xor(send, 4);
        }
      }
      {
        bool hi = (lane & 2) != 0;
        float keep = hi ? v[1] : v[0], send = hi ? v[0] : v[1];
        v[0] = keep + __shfl_xor(send, 2);
      }
      float gv = v[0] + gq0;         // lane: idx=(lane>>1)&31
      gq0 = gq0n;
      float gf = __shfl_down(gv, 16);
      float gg = __shfl_down(gv, 32);
      float go = __shfl_down(gv, 48);
      if (owner) {
        float i_ = 1.f / (1.f + expf(-gv));
        float f_ = 1.f / (1.f + expf(-gf));
        float ci = tanhf(gg);
        float o_ = 1.f / (1.f + expf(-go));
        cst0 = f_ * cst0 + i_ * ci;
        float hnew = o_ * tanhf(cst0);
        __hip_atomic_store(hb0 + ((step + 1) & 1) * 6144 + bb * 768 + unit, hnew,
                           __ATOMIC_RELAXED, __HIP_MEMORY_SCOPE_AGENT);
        hs[((size_t)(bb * 512 + t)) * 1536 + unit] = hnew;
      }
    }

    // ---------------- dir 1 half-step ----------------
    if (tid < NWG) {                 // A1: poll dir1 producers
      const int* fp = &f1[tid * 8];
      while (__hip_atomic_load(fp, __ATOMIC_RELAXED, __HIP_MEMORY_SCOPE_AGENT) < step)
        __builtin_amdgcn_s_sleep(2);
    }
    {                                // B1: stage h1(step)
      const float* hsrc = hb1 + (step & 1) * 6144;
#pragma unroll
      for (int i = 0; i < 6; ++i) {
        int id2 = i * 256 + tid;
        int b2 = id2 / 192;
        int r4 = (id2 - b2 * 192) * 4;
        const u64* src = (const u64*)(hsrc + b2 * 768 + r4);
        u64 lo = __hip_atomic_load(src,     __ATOMIC_RELAXED, __HIP_MEMORY_SCOPE_AGENT);
        u64 hi = __hip_atomic_load(src + 1, __ATOMIC_RELAXED, __HIP_MEMORY_SCOPE_AGENT);
        float* dst = &hlds1[b2 * 772 + r4];
        *(u64*)dst = lo; *(u64*)(dst + 2) = hi;
      }
    }
    __syncthreads();                 // C1 (drains D0's hb0(step+1) stores)
    if (tid == 0)                    // P0: hb0(step+1) now visible
      __hip_atomic_store(&f0[wg * 8], step + 1, __ATOMIC_RELAXED, __HIP_MEMORY_SCOPE_AGENT);

    {                                // D1
      const float* hp = hlds1 + lane * 4;
      float v[32];
#pragma unroll
      for (int i = 0; i < 32; ++i) v[i] = 0.f;
#pragma unroll
      for (int jj = 0; jj < 3; ++jj)
#pragma unroll
        for (int b2 = 0; b2 < 8; ++b2) {
          float4 hv = *(const float4*)(hp + b2 * 772 + jj * 256);
#pragma unroll
          for (int j = 0; j < 4; ++j) {
            float4 w = w1[j][jj];
            v[j * 8 + b2] = fmaf(w.x, hv.x, v[j * 8 + b2]);
            v[j * 8 + b2] = fmaf(w.y, hv.y, v[j * 8 + b2]);
            v[j * 8 + b2] = fmaf(w.z, hv.z, v[j * 8 + b2]);
            v[j * 8 + b2] = fmaf(w.w, hv.w, v[j * 8 + b2]);
          }
        }
      {
        bool hi = (lane & 32) != 0;
#pragma unroll
        for (int i = 0; i < 16; ++i) {
          float keep = hi ? v[i + 16] : v[i], send = hi ? v[i] : v[i + 16];
          v[i] = keep + __shfl_xor(send, 32);
        }
      }
      {
        bool hi = (lane & 16) != 0;
#pragma unroll
        for (int i = 0; i < 8; ++i) {
          float keep = hi ? v[i + 8] : v[i], send = hi ? v[i] : v[i + 8];
          v[i] = keep + __shfl_xor(send, 16);
        }
      }
      {
        bool hi = (lane & 8) != 0;
#pragma unroll
        for (int i = 0; i < 4; ++i) {
          float keep = hi ? v[i + 4] : v[i], send = hi ? v[i] : v[i + 4];
          v[i] = keep + __shfl_xor(send, 8);
        }
      }
      {
        bool hi = (lane & 4) != 0;
#pragma unroll
        for (int i = 0; i < 2; ++i) {
          float keep = hi ? v[i + 2] : v[i], send = hi ? v[i] : v[i + 2];
          v[i] = keep + __shfl_xor(send, 4);
        }
      }
      {
        bool hi = (lane & 2) != 0;
        float keep = hi ? v[1] : v[0], send = hi ? v[0] : v[1];
        v[0] = keep + __shfl_xor(send, 2);
      }
      float gv = v[0] + gq1;
      gq1 = gq1n;
      float gf = __shfl_down(gv, 16);
      float gg = __shfl_down(gv, 32);
      float go = __shfl_down(gv, 48);
      if (owner) {
        float i_ = 1.f / (1.f + expf(-gv));
        float f_ = 1.f / (1.f + expf(-gf));
        float ci = tanhf(gg);
        float o_ = 1.f / (1.f + expf(-go));
        cst1 = f_ * cst1 + i_ * ci;
        float hnew = o_ * tanhf(cst1);
        __hip_atomic_store(hb1 + ((step + 1) & 1) * 6144 + bb * 768 + unit, hnew,
                           __ATOMIC_RELAXED, __HIP_MEMORY_SCOPE_AGENT);
        hs[((size_t)(bb * 512 + t1)) * 1536 + 768 + unit] = hnew;
      }
    }
  }
}

// ---------------------------------------------------------------------------
// fc: em[4096][9] = A[4096][1536] @ fcW[9][1536]^T + fcb. Wave per row.
// ---------------------------------------------------------------------------
__global__ __launch_bounds__(256) void k_fc(const float* __restrict__ A,
                                            const float* __restrict__ Wf,
                                            const float* __restrict__ bf,
                                            float* __restrict__ out) {
  __shared__ float Wl[9 * 1536];
  int tid = threadIdx.x;
  for (int i = tid; i < 9 * 1536; i += 256) Wl[i] = Wf[i];
  __syncthreads();
  int lane = tid & 63, wv = tid >> 6;
  int row = blockIdx.x * 4 + wv;
  const float* a = A + (size_t)row * 1536;
  float acc[9];
#pragma unroll
  for (int c = 0; c < 9; ++c) acc[c] = 0.f;
  for (int i = 0; i < 24; ++i) {
    float av = a[lane + i * 64];
#pragma unroll
    for (int c = 0; c < 9; ++c) acc[c] += av * Wl[c * 1536 + lane + i * 64];
  }
#pragma unroll
  for (int c = 0; c < 9; ++c) {
#pragma unroll
    for (int m = 1; m < 64; m <<= 1) acc[c] += __shfl_xor(acc[c], m);
  }
  if (lane == 0) {
#pragma unroll
    for (int c = 0; c < 9; ++c) out[(size_t)row * 9 + c] = acc[c] + bf[c];
  }
}

// ---------------------------------------------------------------------------
// CRF: forward logsumexp + numerator + Viterbi + backtrace. Single block.
// ---------------------------------------------------------------------------
__global__ __launch_bounds__(128) void k_crf(const float* __restrict__ em,
                                             const int* __restrict__ labels,
                                             const float* __restrict__ cs,
                                             const float* __restrict__ ce,
                                             const float* __restrict__ ct,
                                             float* __restrict__ out) {
  __shared__ float trans[9][12];
  __shared__ float ab[2][8][9];
  __shared__ float vb[2][8][9];
  __shared__ unsigned char bps[511][8][9];
  __shared__ float red[128];
  __shared__ float lz[8];
  int tid = threadIdx.x;
  if (tid < 81) trans[tid / 9][tid % 9] = ct[tid];
  if (tid < 72) {
    int b = tid / 9, c = tid % 9;
    float v = cs[c] + em[(b * 512) * 9 + c];
    ab[0][b][c] = v;
    vb[0][b][c] = v;
  }
  __syncthreads();
  for (int t = 1; t < 512; ++t) {
    int rp = (t - 1) & 1, wp = t & 1;
    if (tid < 72) {
      int b = tid / 9, cn = tid % 9;
      float e = em[(b * 512 + t) * 9 + cn];
      float m = -1e30f, vm = -1e30f;
      int bp = 0;
#pragma unroll
      for (int cp = 0; cp < 9; ++cp) {
        float x = ab[rp][b][cp] + trans[cp][cn];
        m = fmaxf(m, x);
        float y = vb[rp][b][cp] + trans[cp][cn];
        if (y > vm) { vm = y; bp = cp; }
      }
      float ssum = 0.f;
#pragma unroll
      for (int cp = 0; cp < 9; ++cp)
        ssum += expf(ab[rp][b][cp] + trans[cp][cn] - m);
      ab[wp][b][cn] = m + logf(ssum) + e;
      vb[wp][b][cn] = vm + e;
      bps[t - 1][b][cn] = (unsigned char)bp;
    }
    __syncthreads();
  }
  float part = 0.f;
  for (int idx = tid; idx < 4096; idx += 128) {
    int b = idx >> 9, t = idx & 511;
    int tg = labels[b * 512 + t];
    part += em[(b * 512 + t) * 9 + tg];
    if (t < 511) part += trans[tg][labels[b * 512 + t + 1]];
  }
  if (tid < 8) part += cs[labels[tid * 512]] + ce[labels[tid * 512 + 511]];
  red[tid] = part;
  __syncthreads();
  for (int s2 = 64; s2 > 0; s2 >>= 1) {
    if (tid < s2) red[tid] += red[tid + s2];
    __syncthreads();
  }
  if (tid < 8) {
    int b = tid;
    float m = -1e30f;
#pragma unroll
    for (int c = 0; c < 9; ++c) m = fmaxf(m, ab[1][b][c] + ce[c]);
    float ssum = 0.f;
#pragma unroll
    for (int c = 0; c < 9; ++c) ssum += expf(ab[1][b][c] + ce[c] - m);
    lz[b] = m + logf(ssum);
  }
  __syncthreads();
  if (tid == 0) {
    float z = 0.f;
#pragma unroll
    for (int b = 0; b < 8; ++b) z += lz[b];
    out[0] = -(red[0] - z);
  }
  if (tid < 8) {
    int b = tid;
    float bv2 = vb[1][b][0] + ce[0];
    int best = 0;
#pragma unroll
    for (int c = 1; c < 9; ++c) {
      float y = vb[1][b][c] + ce[c];
      if (y > bv2) { bv2 = y; best = c; }
    }
    out[1 + b * 512 + 511] = (float)best;
    int tg = best;
    for (int t = 510; t >= 0; --t) {
      tg = bps[t][b][tg];
      out[1 + b * 512 + t] = (float)tg;
    }
  }
}

// ---------------------------------------------------------------------------
extern "C" void kernel_launch(void* const* d_in, const int* in_sizes, int n_in,
                              void* d_out, int out_size, void* d_ws, size_t ws_size,
                              hipStream_t stream) {
  (void)in_sizes; (void)n_in; (void)out_size; (void)ws_size;
  const int*   ids    = (const int*)d_in[0];
  const int*   labels = (const int*)d_in[1];
  const float* emb    = (const float*)d_in[2];
  const float* hwWh   = (const float*)d_in[3];
  const float* hwbh   = (const float*)d_in[4];
  const float* hwWt   = (const float*)d_in[5];
  const float* hwbt   = (const float*)d_in[6];
  const float* ipw    = (const float*)d_in[7];
  const float* ipb    = (const float*)d_in[8];
  const float* opw    = (const float*)d_in[9];
  const float* opb    = (const float*)d_in[10];
  const float* l0Wih  = (const float*)d_in[11];
  const float* l0Whh  = (const float*)d_in[12];
  const float* l0b    = (const float*)d_in[13];
  const float* l1Wih  = (const float*)d_in[14];
  const float* l1Whh  = (const float*)d_in[15];
  const float* l1b    = (const float*)d_in[16];
  const float* fcW    = (const float*)d_in[17];
  const float* fcb    = (const float*)d_in[18];
  const float* cs     = (const float*)d_in[19];
  const float* ce     = (const float*)d_in[20];
  const float* ct     = (const float*)d_in[21];

  float* ws   = (float*)d_ws;
  float* x0   = ws;                 // 3,145,728
  float* gbuf = ws + 3145728;       // 25,165,824 (hh|tt, later qkv, later gates)
  float* hh   = gbuf;
  float* tt   = gbuf + 3145728;
  float* qkv  = gbuf + 6291456;
  float* x1   = ws + 28311552;      // 3,145,728
  float* hs0  = ws + 31457280;      // 6,291,456
  float* hs1  = ws + 37748736;      // 6,291,456
  float* em   = ws + 44040192;      // 36,864
  float* hbuf = ws + 44077056;      // 24,576 floats (hb0[2][6144] | hb1[2][6144])
  int*   flags = (int*)(ws + 44101632);  // 2 * 192*8 ints

  dim3 g768(6, 32), g2304(18, 32), g6144(48, 32);

  k_embed<<<BS_, 192, 0, stream>>>(ids, emb, x0);
  k_gemm<<<g768, 256, 0, stream>>>(x0, hwWh, hwbh, hh, BS_, 768, 768, 1, 0);
  k_gemm<<<g768, 256, 0, stream>>>(x0, hwWt, hwbt, tt, BS_, 768, 768, 2, 0);
  k_highway<<<768, 256, 0, stream>>>(x0, hh, tt);
  k_gemm<<<g2304, 256, 0, stream>>>(x0, ipw, ipb, qkv, BS_, 2304, 768, 0, 0);
  k_attn<<<dim3(64, 32), 256, 0, stream>>>(qkv, x0);
  k_gemm<<<g768, 256, 0, stream>>>(x0, opw, opb, x1, BS_, 768, 768, 0, 0);

  k_gemm<<<g6144, 256, 0, stream>>>(x1, l0Wih, l0b, gbuf, BS_, 6144, 768, 0, 1);
  hipMemsetAsync(hbuf, 0, (24576 + 2 * NWG * 8) * sizeof(float), stream);
  k_lstm<<<NWG, 256, 0, stream>>>(gbuf, l0Whh, hbuf, hs0, flags);

  k_gemm<<<g6144, 256, 0, stream>>>(hs0, l1Wih, l1b, gbuf, BS_, 6144, 1536, 0, 1);
  hipMemsetAsync(hbuf, 0, (24576 + 2 * NWG * 8) * sizeof(float), stream);
  k_lstm<<<NWG, 256, 0, stream>>>(gbuf, l1Whh, hbuf, hs1, flags);

  k_fc<<<1024, 256, 0, stream>>>(hs1, fcW, fcb, em);
  k_crf<<<1, 128, 0, stream>>>(em, labels, cs, ce, ct, (float*)d_out);
}

// Round 8
// 8151.891 us; speedup vs baseline: 1.3048x; 1.3048x over previous
//
#include <hip/hip_runtime.h>
#include <cstdint>

#define B_   8
#define S_   512
#define D_   768
#define C_   9
#define BS_  4096   // B*S

typedef unsigned long long u64;

// ---------------------------------------------------------------------------
// embedding gather: x[row][0:768] = emb[ids[row]][0:768]
// ---------------------------------------------------------------------------
__global__ __launch_bounds__(192) void k_embed(const int* __restrict__ ids,
                                               const float* __restrict__ emb,
                                               float* __restrict__ x) {
  int row = blockIdx.x;
  int id = ids[row];
  const float4* src = (const float4*)(emb + (size_t)id * D_);
  float4* dst = (float4*)(x + (size_t)row * D_);
  dst[threadIdx.x] = src[threadIdx.x];
}

// ---------------------------------------------------------------------------
// generic fp32 GEMM: C[M,N] = A[M,K] @ W[N,K]^T + bias[N]
// act: 0 none 1 relu 2 sigmoid ; mode: 0 row-major C, 1 lstm-gates layout
// gates layout: C[((dir*512+t)*96+grp)*256 + u*32 + g*8 + bb]
// Double-buffered LDS: prefetch next K-tile to regs, ONE sync per K-step.
// ---------------------------------------------------------------------------
#define GIDX(k, m) ((k)*144 + (m) + (((m) >> 5) << 2))

__global__ __launch_bounds__(256) void k_gemm(const float* __restrict__ A,
                                              const float* __restrict__ W,
                                              const float* __restrict__ bias,
                                              float* __restrict__ C,
                                              int M, int N, int K, int act, int mode) {
  __shared__ float As[2][2304];
  __shared__ float Bs[2][2304];
  int bm0 = blockIdx.y * 128, bn0 = blockIdx.x * 128;
  int tid = threadIdx.x;
  int tm = tid >> 4, tn = tid & 15;
  int r0 = tid >> 2, kq = (tid & 3) * 4;
  const float* Aptr = A + (size_t)(bm0 + r0) * K + kq;
  const float* Wptr = W + (size_t)(bn0 + r0) * K + kq;
  const size_t rowK = (size_t)64 * K;

  float acc[8][8];
#pragma unroll
  for (int i = 0; i < 8; ++i)
#pragma unroll
    for (int j = 0; j < 8; ++j) acc[i][j] = 0.f;

#define STAGE(buf, A0, A1, B0, B1)                                           \
  {                                                                          \
    As[buf][GIDX(kq + 0, r0)] = A0.x; As[buf][GIDX(kq + 1, r0)] = A0.y;      \
    As[buf][GIDX(kq + 2, r0)] = A0.z; As[buf][GIDX(kq + 3, r0)] = A0.w;      \
    As[buf][GIDX(kq + 0, r0 + 64)] = A1.x; As[buf][GIDX(kq + 1, r0 + 64)] = A1.y; \
    As[buf][GIDX(kq + 2, r0 + 64)] = A1.z; As[buf][GIDX(kq + 3, r0 + 64)] = A1.w; \
    Bs[buf][GIDX(kq + 0, r0)] = B0.x; Bs[buf][GIDX(kq + 1, r0)] = B0.y;      \
    Bs[buf][GIDX(kq + 2, r0)] = B0.z; Bs[buf][GIDX(kq + 3, r0)] = B0.w;      \
    Bs[buf][GIDX(kq + 0, r0 + 64)] = B1.x; Bs[buf][GIDX(kq + 1, r0 + 64)] = B1.y; \
    Bs[buf][GIDX(kq + 2, r0 + 64)] = B1.z; Bs[buf][GIDX(kq + 3, r0 + 64)] = B1.w; \
  }

  {
    float4 a0 = *(const float4*)(Aptr);
    float4 a1 = *(const float4*)(Aptr + rowK);
    float4 b0 = *(const float4*)(Wptr);
    float4 b1 = *(const float4*)(Wptr + rowK);
    STAGE(0, a0, a1, b0, b1);
  }
  __syncthreads();
  int cur = 0;

  for (int k0 = 0; k0 < K; k0 += 16) {
    bool more = (k0 + 16) < K;
    float4 na0, na1, nb0, nb1;
    if (more) {
      na0 = *(const float4*)(Aptr + k0 + 16);
      na1 = *(const float4*)(Aptr + rowK + k0 + 16);
      nb0 = *(const float4*)(Wptr + k0 + 16);
      nb1 = *(const float4*)(Wptr + rowK + k0 + 16);
    }
#pragma unroll
    for (int kk = 0; kk < 16; ++kk) {
      float a[8], b[8];
      *(float4*)&a[0] = *(const float4*)&As[cur][GIDX(kk, tm * 8)];
      *(float4*)&a[4] = *(const float4*)&As[cur][GIDX(kk, tm * 8 + 4)];
      *(float4*)&b[0] = *(const float4*)&Bs[cur][GIDX(kk, tn * 8)];
      *(float4*)&b[4] = *(const float4*)&Bs[cur][GIDX(kk, tn * 8 + 4)];
#pragma unroll
      for (int i = 0; i < 8; ++i)
#pragma unroll
        for (int j = 0; j < 8; ++j) acc[i][j] += a[i] * b[j];
    }
    if (more) {
      STAGE(cur ^ 1, na0, na1, nb0, nb1);
      __syncthreads();
      cur ^= 1;
    }
  }

  float bv[8];
#pragma unroll
  for (int j = 0; j < 8; ++j) bv[j] = bias[bn0 + tn * 8 + j];
#pragma unroll
  for (int i = 0; i < 8; ++i) {
    int row = bm0 + tm * 8 + i;
    float o[8];
#pragma unroll
    for (int j = 0; j < 8; ++j) {
      float v = acc[i][j] + bv[j];
      if (act == 1) v = fmaxf(v, 0.f);
      else if (act == 2) v = 1.f / (1.f + expf(-v));
      o[j] = v;
    }
    if (mode == 0) {
      float* cp = C + (size_t)row * N + bn0 + tn * 8;
      *(float4*)cp = make_float4(o[0], o[1], o[2], o[3]);
      *(float4*)(cp + 4) = make_float4(o[4], o[5], o[6], o[7]);
    } else {
      int bb = row >> 9, t = row & 511;
#pragma unroll
      for (int j = 0; j < 8; ++j) {
        unsigned n = bn0 + tn * 8 + j;
        unsigned dir = n / 3072u;
        unsigned n2 = n - dir * 3072u;
        unsigned g = n2 / 768u;
        unsigned rem = n2 - g * 768u;
        unsigned grp = rem >> 3, u = rem & 7;
        C[(((size_t)(dir * 512 + t) * 96 + grp) << 8) + u * 32 + g * 8 + bb] = o[j];
      }
    }
  }
}

// ---------------------------------------------------------------------------
// highway combine (in place): x = t*hh + (1-t)*x
// ---------------------------------------------------------------------------
__global__ __launch_bounds__(256) void k_highway(float* __restrict__ x,
                                                 const float* __restrict__ hh,
                                                 const float* __restrict__ tt) {
  const int n4 = BS_ * D_ / 4;
  for (int i = blockIdx.x * 256 + threadIdx.x; i < n4; i += gridDim.x * 256) {
    float4 xv = ((const float4*)x)[i];
    float4 hv = ((const float4*)hh)[i];
    float4 tv = ((const float4*)tt)[i];
    xv.x = tv.x * hv.x + (1.f - tv.x) * xv.x;
    xv.y = tv.y * hv.y + (1.f - tv.y) * xv.y;
    xv.z = tv.z * hv.z + (1.f - tv.z) * xv.z;
    xv.w = tv.w * hv.w + (1.f - tv.w) * xv.w;
    ((float4*)x)[i] = xv;
  }
}

// ---------------------------------------------------------------------------
// multi-head attention. qkv: [4096][2304] (q|k|v). out: [4096][768].
// ---------------------------------------------------------------------------
__global__ __launch_bounds__(256) void k_attn(const float* __restrict__ qkv,
                                              float* __restrict__ out) {
  __shared__ float Qs[16 * 100];
  __shared__ float Ks[32 * 101];
  __shared__ float Ps[16 * 513];
  int bh = blockIdx.x;          // 0..63
  int b = bh >> 3, h = bh & 7;
  int q0 = blockIdx.y * 16;
  int tid = threadIdx.x;
  const float scale = 0.10206207261596577f;  // 1/sqrt(96)

  const float* qb = qkv + (size_t)(b * 512 + q0) * 2304 + h * 96;
  for (int i = tid; i < 16 * 96; i += 256) {
    int r = i / 96, c = i - r * 96;
    Qs[r * 100 + c] = qb[(size_t)r * 2304 + c];
  }
  int qi = tid >> 4, kseg = tid & 15;

  for (int kt = 0; kt < 16; ++kt) {
    __syncthreads();
    const float* kb = qkv + (size_t)(b * 512 + kt * 32) * 2304 + 768 + h * 96;
    for (int i = tid; i < 32 * 96; i += 256) {
      int r = i / 96, c = i - r * 96;
      Ks[r * 101 + c] = kb[(size_t)r * 2304 + c];
    }
    __syncthreads();
    int kj0 = kseg * 2;
    float s0 = 0.f, s1 = 0.f;
    const float* qrow = &Qs[qi * 100];
    const float* k0p = &Ks[kj0 * 101];
    const float* k1p = &Ks[(kj0 + 1) * 101];
#pragma unroll 8
    for (int d = 0; d < 96; ++d) {
      float qv = qrow[d];
      s0 += qv * k0p[d];
      s1 += qv * k1p[d];
    }
    Ps[qi * 513 + kt * 32 + kj0] = s0 * scale;
    Ps[qi * 513 + kt * 32 + kj0 + 1] = s1 * scale;
  }
  __syncthreads();

  {
    float m = -1e30f;
    for (int j = 0; j < 32; ++j) m = fmaxf(m, Ps[qi * 513 + kseg + j * 16]);
    m = fmaxf(m, __shfl_xor(m, 1)); m = fmaxf(m, __shfl_xor(m, 2));
    m = fmaxf(m, __shfl_xor(m, 4)); m = fmaxf(m, __shfl_xor(m, 8));
    float sum = 0.f;
    for (int j = 0; j < 32; ++j) {
      int idx = qi * 513 + kseg + j * 16;
      float e = expf(Ps[idx] - m);
      Ps[idx] = e;
      sum += e;
    }
    sum += __shfl_xor(sum, 1); sum += __shfl_xor(sum, 2);
    sum += __shfl_xor(sum, 4); sum += __shfl_xor(sum, 8);
    float inv = 1.f / sum;
    for (int j = 0; j < 32; ++j) Ps[qi * 513 + kseg + j * 16] *= inv;
  }

  float acc[6] = {0.f, 0.f, 0.f, 0.f, 0.f, 0.f};
  int d0 = kseg * 6;
  for (int kt = 0; kt < 16; ++kt) {
    __syncthreads();
    const float* vb = qkv + (size_t)(b * 512 + kt * 32) * 2304 + 1536 + h * 96;
    for (int i = tid; i < 32 * 96; i += 256) {
      int r = i / 96, c = i - r * 96;
      Ks[r * 101 + c] = vb[(size_t)r * 2304 + c];
    }
    __syncthreads();
#pragma unroll 4
    for (int kj = 0; kj < 32; ++kj) {
      float p = Ps[qi * 513 + kt * 32 + kj];
      const float* vrow = &Ks[kj * 101 + d0];
#pragma unroll
      for (int u = 0; u < 6; ++u) acc[u] += p * vrow[u];
    }
  }
  float* ob = out + (size_t)(b * 512 + q0 + qi) * 768 + h * 96 + d0;
#pragma unroll
  for (int u = 0; u < 6; ++u) ob[u] = acc[u];
}

// ---------------------------------------------------------------------------
// persistent BiLSTM recurrence (round-3 protocol, verbatim), one change:
// hs history store moved AFTER the flag release -> its HBM drain overlaps the
// poll window instead of sitting on the critical pre-flag sync.
// ---------------------------------------------------------------------------
#define NWGD 96
__global__ __launch_bounds__(256, 1) void k_lstm(const float* __restrict__ gates,
                                                 const float* __restrict__ Whh,
                                                 float* __restrict__ hbuf,
                                                 float* __restrict__ hs,
                                                 int* __restrict__ flags) {
  __shared__ float hlds[8 * 772];    // 24.7 KB
  int tid = threadIdx.x;
  int wg = blockIdx.x;
  int dir = wg / NWGD;
  int grp = wg % NWGD;
  int rg = tid >> 5;                 // unit u, 0..7
  int ks = tid & 31;                 // k-slice

  // weights in registers (96 VGPRs), coalesced along ks
  float4 w4[4][6];
#pragma unroll
  for (int j = 0; j < 4; ++j) {
    const float* wp = Whh + ((size_t)dir * 3072 + j * 768 + grp * 8 + rg) * 768 + ks * 4;
#pragma unroll
    for (int jj = 0; jj < 6; ++jj)
      w4[j][jj] = *(const float4*)(wp + jj * 128);
  }

  float* hb = hbuf + (size_t)dir * 2 * 6144;   // [parity][bb][768]
  const float* gbase = gates + (size_t)dir * 512 * 24576 + grp * 256 + tid;
  const float* hp = hlds + ks * 4;
  float cst = 0.f;

  for (int step = 0; step < 512; ++step) {
    int t = dir ? (511 - step) : step;
    float gqv = gbase[(size_t)t * 24576];

    // stage h(t) into LDS via agent-scope u64 loads
#pragma unroll
    for (int i = 0; i < 3; ++i) {
      int idx = i * 256 + tid;            // 0..767
      int b2 = idx / 96;
      int kq = (idx - b2 * 96) * 8;
      const u64* src = (const u64*)(hb + (step & 1) * 6144 + b2 * 768 + kq);
      u64 lo  = __hip_atomic_load(src + 0, __ATOMIC_RELAXED, __HIP_MEMORY_SCOPE_AGENT);
      u64 hi  = __hip_atomic_load(src + 1, __ATOMIC_RELAXED, __HIP_MEMORY_SCOPE_AGENT);
      u64 lo2 = __hip_atomic_load(src + 2, __ATOMIC_RELAXED, __HIP_MEMORY_SCOPE_AGENT);
      u64 hi2 = __hip_atomic_load(src + 3, __ATOMIC_RELAXED, __HIP_MEMORY_SCOPE_AGENT);
      float* dst = &hlds[b2 * 772 + kq];
      *(u64*)(dst + 0) = lo;
      *(u64*)(dst + 2) = hi;
      *(u64*)(dst + 4) = lo2;
      *(u64*)(dst + 6) = hi2;
    }
    __syncthreads();   // hlds ready

    // partials: v[g*8+bb] over my 24-wide interleaved k-slice
    float v[32];
#pragma unroll
    for (int i = 0; i < 32; ++i) v[i] = 0.f;
#pragma unroll
    for (int jj = 0; jj < 6; ++jj) {
#pragma unroll
      for (int b2 = 0; b2 < 8; ++b2) {
        float4 hv = *(const float4*)(hp + b2 * 772 + jj * 128);
#pragma unroll
        for (int j = 0; j < 4; ++j) {
          float4 w = w4[j][jj];
          v[j * 8 + b2] = fmaf(w.x, hv.x, v[j * 8 + b2]);
          v[j * 8 + b2] = fmaf(w.y, hv.y, v[j * 8 + b2]);
          v[j * 8 + b2] = fmaf(w.z, hv.z, v[j * 8 + b2]);
          v[j * 8 + b2] = fmaf(w.w, hv.w, v[j * 8 + b2]);
        }
      }
    }

    // reduce-scatter across 32 kslices: lane ks ends with sum for idx=ks
    {
      bool hi = (ks & 16) != 0;
#pragma unroll
      for (int i = 0; i < 16; ++i) {
        float keep = hi ? v[i + 16] : v[i];
        float send = hi ? v[i] : v[i + 16];
        v[i] = keep + __shfl_xor(send, 16);
      }
    }
    {
      bool hi = (ks & 8) != 0;
#pragma unroll
      for (int i = 0; i < 8; ++i) {
        float keep = hi ? v[i + 8] : v[i];
        float send = hi ? v[i] : v[i + 8];
        v[i] = keep + __shfl_xor(send, 8);
      }
    }
    {
      bool hi = (ks & 4) != 0;
#pragma unroll
      for (int i = 0; i < 4; ++i) {
        float keep = hi ? v[i + 4] : v[i];
        float send = hi ? v[i] : v[i + 4];
        v[i] = keep + __shfl_xor(send, 4);
      }
    }
    {
      bool hi = (ks & 2) != 0;
#pragma unroll
      for (int i = 0; i < 2; ++i) {
        float keep = hi ? v[i + 2] : v[i];
        float send = hi ? v[i] : v[i + 2];
        v[i] = keep + __shfl_xor(send, 2);
      }
    }
    {
      bool hi = (ks & 1) != 0;
      float keep = hi ? v[1] : v[0];
      float send = hi ? v[0] : v[1];
      v[0] = keep + __shfl_xor(send, 1);
    }

    float gv = v[0] + gqv;            // lane ks: gate g=ks>>3, batch bb=ks&7
    float gf = __shfl_down(gv, 8);
    float gg = __shfl_down(gv, 16);
    float go = __shfl_down(gv, 24);
    float hnew = 0.f;
    if (ks < 8) {                     // owner of (unit=rg, bb=ks)
      float i_ = 1.f / (1.f + expf(-gv));
      float f_ = 1.f / (1.f + expf(-gf));
      float ci = tanhf(gg);
      float o_ = 1.f / (1.f + expf(-go));
      cst = f_ * cst + i_ * ci;
      hnew = o_ * tanhf(cst);
      __hip_atomic_store(hb + (size_t)((step + 1) & 1) * 6144 + ks * 768 + grp * 8 + rg,
                         hnew, __ATOMIC_RELAXED, __HIP_MEMORY_SCOPE_AGENT);
    }

    // per-WG monotonic flag barrier (per direction)
    __syncthreads();   // drains hb stores (LLC) -- hs no longer on this path
    if (tid == 0)
      __hip_atomic_store(&flags[wg * 32], step + 1, __ATOMIC_RELAXED, __HIP_MEMORY_SCOPE_AGENT);
    if (ks < 8)        // fire-and-forget history write; drains during poll
      hs[((size_t)(ks * 512 + t)) * 1536 + dir * 768 + grp * 8 + rg] = hnew;
    if (tid < NWGD) {
      const int* fp = &flags[(dir * NWGD + tid) * 32];
      while (__hip_atomic_load(fp, __ATOMIC_RELAXED, __HIP_MEMORY_SCOPE_AGENT) <= step)
        __builtin_amdgcn_s_sleep(2);
    }
    __syncthreads();   // all flags observed -> remote h stores visible
  }
}

// ---------------------------------------------------------------------------
// fc: em[4096][9] = A[4096][1536] @ fcW[9][1536]^T + fcb. Wave per row.
// ---------------------------------------------------------------------------
__global__ __launch_bounds__(256) void k_fc(const float* __restrict__ A,
                                            const float* __restrict__ Wf,
                                            const float* __restrict__ bf,
                                            float* __restrict__ out) {
  __shared__ float Wl[9 * 1536];
  int tid = threadIdx.x;
  for (int i = tid; i < 9 * 1536; i += 256) Wl[i] = Wf[i];
  __syncthreads();
  int lane = tid & 63, wv = tid >> 6;
  int row = blockIdx.x * 4 + wv;
  const float* a = A + (size_t)row * 1536;
  float acc[9];
#pragma unroll
  for (int c = 0; c < 9; ++c) acc[c] = 0.f;
  for (int i = 0; i < 24; ++i) {
    float av = a[lane + i * 64];
#pragma unroll
    for (int c = 0; c < 9; ++c) acc[c] += av * Wl[c * 1536 + lane + i * 64];
  }
#pragma unroll
  for (int c = 0; c < 9; ++c) {
#pragma unroll
    for (int m = 1; m < 64; m <<= 1) acc[c] += __shfl_xor(acc[c], m);
  }
  if (lane == 0) {
#pragma unroll
    for (int c = 0; c < 9; ++c) out[(size_t)row * 9 + c] = acc[c] + bf[c];
  }
}

// ---------------------------------------------------------------------------
// CRF: one block of 512 threads; wave b = batch b (independent recursions!).
// Lane cn (<9) holds alpha/viterbi state; 9-term LSE via __shfl; em prefetch
// one step ahead; NO __syncthreads in the 511-step loop. Backpointers in LDS.
// ---------------------------------------------------------------------------
__global__ __launch_bounds__(512) void k_crf(const float* __restrict__ em,
                                             const int* __restrict__ labels,
                                             const float* __restrict__ cs,
                                             const float* __restrict__ ce,
                                             const float* __restrict__ ct,
                                             float* __restrict__ out) {
  __shared__ float trans_s[81];
  __shared__ unsigned char bps[8][511][12];
  __shared__ float partres[16];       // [0..7]=num_b, [8..15]=logZ_b
  int tid = threadIdx.x;
  int b = tid >> 6;                   // wave = batch
  int lane = tid & 63;
  bool act = lane < 9;
  if (tid < 81) trans_s[tid] = ct[tid];
  __syncthreads();

  float tcol[9];
#pragma unroll
  for (int cp = 0; cp < 9; ++cp) tcol[cp] = act ? trans_s[cp * 9 + lane] : 0.f;

  float a_ = -1e30f, v_ = -1e30f;
  if (act) {
    float e0 = em[((size_t)b * 512) * 9 + lane];
    a_ = cs[lane] + e0;
    v_ = a_;
  }

  float e = act ? em[((size_t)b * 512 + 1) * 9 + lane] : 0.f;
  for (int t = 1; t < 512; ++t) {
    float e_nxt = 0.f;
    if (act && t < 511) e_nxt = em[((size_t)b * 512 + t + 1) * 9 + lane];
    float m = -1e30f, vm = -1e30f;
    int bp = 0;
    float xs[9];
#pragma unroll
    for (int cp = 0; cp < 9; ++cp) {
      float ap = __shfl(a_, cp);
      float vp = __shfl(v_, cp);
      float x = ap + tcol[cp];
      xs[cp] = x;
      m = fmaxf(m, x);
      float y = vp + tcol[cp];
      if (y > vm) { vm = y; bp = cp; }
    }
    float ssum = 0.f;
#pragma unroll
    for (int cp = 0; cp < 9; ++cp) ssum += expf(xs[cp] - m);
    if (act) {
      a_ = m + logf(ssum) + e;
      v_ = vm + e;
      bps[b][t - 1][lane] = (unsigned char)bp;
    }
    e = e_nxt;
  }

  // logZ_b (LSE over lanes 0..8; inactive lanes = -1e30 contribute 0)
  float fin = act ? a_ + ce[lane] : -1e30f;
  float vfin = act ? v_ + ce[lane] : -1e30f;
  float m2 = fin;
  m2 = fmaxf(m2, __shfl_xor(m2, 1)); m2 = fmaxf(m2, __shfl_xor(m2, 2));
  m2 = fmaxf(m2, __shfl_xor(m2, 4)); m2 = fmaxf(m2, __shfl_xor(m2, 8));
  float s2 = expf(fin - m2);
  s2 += __shfl_xor(s2, 1); s2 += __shfl_xor(s2, 2);
  s2 += __shfl_xor(s2, 4); s2 += __shfl_xor(s2, 8);
  float logZ = m2 + logf(s2);

  // viterbi last tag: argmax over lanes 0..8, first-max tie-break
  float bv = vfin; int bi = lane;
#pragma unroll
  for (int s = 1; s < 16; s <<= 1) {
    float ov = __shfl_xor(bv, s);
    int oi = __shfl_xor(bi, s);
    if (ov > bv || (ov == bv && oi < bi)) { bv = ov; bi = oi; }
  }

  // numerator (lane-parallel over t)
  float np = 0.f;
  for (int t = lane; t < 512; t += 64) {
    int tg = labels[b * 512 + t];
    np += em[((size_t)b * 512 + t) * 9 + tg];
    if (t < 511) np += trans_s[tg * 9 + labels[b * 512 + t + 1]];
  }
#pragma unroll
  for (int s = 1; s < 64; s <<= 1) np += __shfl_xor(np, s);

  if (lane == 0) {
    np += cs[labels[b * 512]] + ce[labels[b * 512 + 511]];
    partres[b] = np;
    partres[8 + b] = logZ;
    // backtrace
    out[1 + b * 512 + 511] = (float)bi;
    int tg = bi;
    for (int t = 510; t >= 0; --t) {
      tg = bps[b][t][tg];
      out[1 + b * 512 + t] = (float)tg;
    }
  }
  __syncthreads();
  if (tid == 0) {
    float acc = 0.f;
#pragma unroll
    for (int b2 = 0; b2 < 8; ++b2) acc += partres[b2] - partres[8 + b2];
    out[0] = -acc;
  }
}

// ---------------------------------------------------------------------------
extern "C" void kernel_launch(void* const* d_in, const int* in_sizes, int n_in,
                              void* d_out, int out_size, void* d_ws, size_t ws_size,
                              hipStream_t stream) {
  (void)in_sizes; (void)n_in; (void)out_size; (void)ws_size;
  const int*   ids    = (const int*)d_in[0];
  const int*   labels = (const int*)d_in[1];
  const float* emb    = (const float*)d_in[2];
  const float* hwWh   = (const float*)d_in[3];
  const float* hwbh   = (const float*)d_in[4];
  const float* hwWt   = (const float*)d_in[5];
  const float* hwbt   = (const float*)d_in[6];
  const float* ipw    = (const float*)d_in[7];
  const float* ipb    = (const float*)d_in[8];
  const float* opw    = (const float*)d_in[9];
  const float* opb    = (const float*)d_in[10];
  const float* l0Wih  = (const float*)d_in[11];
  const float* l0Whh  = (const float*)d_in[12];
  const float* l0b    = (const float*)d_in[13];
  const float* l1Wih  = (const float*)d_in[14];
  const float* l1Whh  = (const float*)d_in[15];
  const float* l1b    = (const float*)d_in[16];
  const float* fcW    = (const float*)d_in[17];
  const float* fcb    = (const float*)d_in[18];
  const float* cs     = (const float*)d_in[19];
  const float* ce     = (const float*)d_in[20];
  const float* ct     = (const float*)d_in[21];

  float* ws   = (float*)d_ws;
  float* x0   = ws;                 // 3,145,728
  float* gbuf = ws + 3145728;       // 25,165,824 (hh|tt, later qkv, later gates)
  float* hh   = gbuf;
  float* tt   = gbuf + 3145728;
  float* qkv  = gbuf + 6291456;
  float* x1   = ws + 28311552;      // 3,145,728
  float* hs0  = ws + 31457280;      // 6,291,456
  float* hs1  = ws + 37748736;      // 6,291,456
  float* em   = ws + 44040192;      // 36,864
  float* hbuf = ws + 44077056;      // 24,576
  int*   flags = (int*)(ws + 44101632);  // 192*32 ints

  dim3 g768(6, 32), g2304(18, 32), g6144(48, 32);

  k_embed<<<BS_, 192, 0, stream>>>(ids, emb, x0);
  k_gemm<<<g768, 256, 0, stream>>>(x0, hwWh, hwbh, hh, BS_, 768, 768, 1, 0);
  k_gemm<<<g768, 256, 0, stream>>>(x0, hwWt, hwbt, tt, BS_, 768, 768, 2, 0);
  k_highway<<<768, 256, 0, stream>>>(x0, hh, tt);
  k_gemm<<<g2304, 256, 0, stream>>>(x0, ipw, ipb, qkv, BS_, 2304, 768, 0, 0);
  k_attn<<<dim3(64, 32), 256, 0, stream>>>(qkv, x0);
  k_gemm<<<g768, 256, 0, stream>>>(x0, opw, opb, x1, BS_, 768, 768, 0, 0);

  k_gemm<<<g6144, 256, 0, stream>>>(x1, l0Wih, l0b, gbuf, BS_, 6144, 768, 0, 1);
  hipMemsetAsync(hbuf, 0, (24576 + 192 * 32) * sizeof(float), stream);
  k_lstm<<<192, 256, 0, stream>>>(gbuf, l0Whh, hbuf, hs0, flags);

  k_gemm<<<g6144, 256, 0, stream>>>(hs0, l1Wih, l1b, gbuf, BS_, 6144, 1536, 0, 1);
  hipMemsetAsync(hbuf, 0, (24576 + 192 * 32) * sizeof(float), stream);
  k_lstm<<<192, 256, 0, stream>>>(gbuf, l1Whh, hbuf, hs1, flags);

  k_fc<<<1024, 256, 0, stream>>>(hs1, fcW, fcb, em);
  k_crf<<<1, 512, 0, stream>>>(em, labels, cs, ce, ct, (float*)d_out);
}